// Round 1
// baseline (9807.363 us; speedup 1.0000x reference)
//
#include <hip/hip_runtime.h>
#include <hip/hip_bf16.h>
#include <math.h>

#define B_ 2
#define S_ 1024
#define E_ 768
#define H_ 12
#define D_ 64
#define I_ 3072
#define V_ 50257
#define RH_ 128
#define MAXD_ 4
#define L_ 4
#define NT (B_*S_)

__device__ __forceinline__ float waveSum(float v){
  #pragma unroll
  for (int o = 32; o > 0; o >>= 1) v += __shfl_xor(v, o);
  return v;
}
__device__ __forceinline__ float waveMax(float v){
  #pragma unroll
  for (int o = 32; o > 0; o >>= 1) v = fmaxf(v, __shfl_xor(v, o));
  return v;
}

// ---------------- embedding: h = tok_emb[ids] + pos_emb[s] ----------------
__global__ void embed_k(const int* __restrict__ ids, const float* __restrict__ tok,
                        const float* __restrict__ pos, float* __restrict__ h){
  int t = blockIdx.x;
  int s = t & (S_ - 1);
  long id = (long)ids[t];
  const float* tr = tok + id * (long)E_;
  const float* pr = pos + (long)s * E_;
  float* hr = h + (long)t * E_;
  for (int e = threadIdx.x; e < E_; e += blockDim.x)
    hr[e] = tr[e] + pr[e];
}

// ---------------- LayerNorm ----------------
__global__ __launch_bounds__(256) void ln_k(const float* __restrict__ x,
                                            const float* __restrict__ g,
                                            const float* __restrict__ b,
                                            float* __restrict__ y){
  int t = blockIdx.x;
  const float* xr = x + (long)t * E_;
  float* yr = y + (long)t * E_;
  float v[3];
  float s = 0.f, s2 = 0.f;
  #pragma unroll
  for (int i = 0; i < 3; i++){
    int e = threadIdx.x + i * 256;
    v[i] = xr[e];
    s += v[i]; s2 += v[i] * v[i];
  }
  __shared__ float rs[4], rq[4];
  float wsv = waveSum(s), wqv = waveSum(s2);
  int wid = threadIdx.x >> 6;
  if ((threadIdx.x & 63) == 0){ rs[wid] = wsv; rq[wid] = wqv; }
  __syncthreads();
  float S = rs[0] + rs[1] + rs[2] + rs[3];
  float Q = rq[0] + rq[1] + rq[2] + rq[3];
  float mu  = S * (1.0f / E_);
  float var = Q * (1.0f / E_) - mu * mu;
  float inv = 1.0f / sqrtf(var + 1e-5f);
  #pragma unroll
  for (int i = 0; i < 3; i++){
    int e = threadIdx.x + i * 256;
    yr[e] = (v[i] - mu) * inv * g[e] + b[e];
  }
}

// ---------------- router: relu(h@w1^T+b1)@w2^T+b2, argmax+1 ----------------
__global__ __launch_bounds__(128) void router_k(const float* __restrict__ h,
                                                const float* __restrict__ w1,
                                                const float* __restrict__ b1,
                                                const float* __restrict__ w2,
                                                const float* __restrict__ b2,
                                                int* __restrict__ dep,
                                                float* __restrict__ out_dep,
                                                float* __restrict__ out_rl){
  int t = blockIdx.x;
  int r = threadIdx.x;
  __shared__ float rh[RH_];
  __shared__ float lg[MAXD_];
  const float* hr = h + (long)t * E_;
  const float* wr = w1 + (long)r * E_;
  float acc = b1[r];
  for (int k = 0; k < E_; k += 4){
    float4 hv = *(const float4*)(hr + k);
    float4 wv = *(const float4*)(wr + k);
    acc = fmaf(hv.x, wv.x, acc); acc = fmaf(hv.y, wv.y, acc);
    acc = fmaf(hv.z, wv.z, acc); acc = fmaf(hv.w, wv.w, acc);
  }
  rh[r] = fmaxf(acc, 0.0f);
  __syncthreads();
  if (r < MAXD_){
    const float* w2r = w2 + r * RH_;
    float a = b2[r];
    for (int k = 0; k < RH_; k++) a = fmaf(rh[k], w2r[k], a);
    lg[r] = a;
    out_rl[t * MAXD_ + r] = a;
  }
  __syncthreads();
  if (r == 0){
    int best = 0; float bv = lg[0];
    #pragma unroll
    for (int d = 1; d < MAXD_; d++) if (lg[d] > bv){ bv = lg[d]; best = d; }  // first-max
    int dd = best + 1;  // MIN_DEPTH
    dep[t] = dd;
    out_dep[t] = (float)dd;
  }
}

// ---------------- GEMM: C[M,N] = A[M,K] @ B[N,K]^T + bias (+epilogue) ----------------
enum { EPI_NONE = 0, EPI_GELU = 1, EPI_RES = 2 };

template<int EPI>
__global__ __launch_bounds__(256) void gemm_bt(const float* __restrict__ A,
                                               const float* __restrict__ Bm,
                                               const float* __restrict__ bias,
                                               const float* __restrict__ R,
                                               float* __restrict__ C,
                                               int M, int N, int K){
  __shared__ float As[16][64];
  __shared__ float Bs[16][64];
  int tid = threadIdx.x;
  int tx = tid & 15, ty = tid >> 4;
  int m0 = blockIdx.y * 64, n0 = blockIdx.x * 64;
  int lr = tid >> 2;             // 0..63: tile row
  int lk = (tid & 3) << 2;       // 0,4,8,12: k offset
  float acc[4][4] = {};
  const float* Arow = A + (long)(m0 + lr) * K + lk;
  const float* Brow = Bm + (long)(n0 + lr) * K + lk;
  bool bvalid = (n0 + lr) < N;
  for (int kt = 0; kt < K; kt += 16){
    float4 av = *(const float4*)(Arow + kt);
    float4 bv = make_float4(0.f, 0.f, 0.f, 0.f);
    if (bvalid) bv = *(const float4*)(Brow + kt);
    __syncthreads();
    As[lk+0][lr] = av.x; As[lk+1][lr] = av.y; As[lk+2][lr] = av.z; As[lk+3][lr] = av.w;
    Bs[lk+0][lr] = bv.x; Bs[lk+1][lr] = bv.y; Bs[lk+2][lr] = bv.z; Bs[lk+3][lr] = bv.w;
    __syncthreads();
    #pragma unroll
    for (int kk = 0; kk < 16; kk++){
      float4 a4 = *(const float4*)&As[kk][ty << 2];
      float4 b4 = *(const float4*)&Bs[kk][tx << 2];
      float aa[4] = {a4.x, a4.y, a4.z, a4.w};
      float bb[4] = {b4.x, b4.y, b4.z, b4.w};
      #pragma unroll
      for (int i = 0; i < 4; i++)
        #pragma unroll
        for (int j = 0; j < 4; j++)
          acc[i][j] = fmaf(aa[i], bb[j], acc[i][j]);
    }
  }
  #pragma unroll
  for (int i = 0; i < 4; i++){
    int m = m0 + (ty << 2) + i;
    float* crow = C + (long)m * N;
    const float* rrow = (EPI == EPI_RES) ? (R + (long)m * N) : nullptr;
    #pragma unroll
    for (int j = 0; j < 4; j++){
      int n = n0 + (tx << 2) + j;
      if (n < N){
        float v = acc[i][j] + (bias ? bias[n] : 0.f);
        if (EPI == EPI_GELU) v = 0.5f * v * (1.0f + erff(v * 0.70710678118654752f));
        if (EPI == EPI_RES)  v += rrow[n];
        crow[n] = v;
      }
    }
  }
}

// ---------------- attention (additive 0/1 float mask, softmax over ALL keys) ----------------
__global__ __launch_bounds__(256) void attn_k(const float* __restrict__ qkv,
                                              const int* __restrict__ dep,
                                              float* __restrict__ out, int depth){
  int s = blockIdx.x, hd = blockIdx.y, b = blockIdx.z;
  __shared__ float qs[64];
  __shared__ float sc[S_];
  __shared__ float rmax[4], rsum[4];
  __shared__ float ov[4][64];
  int tid = threadIdx.x;
  long trow = (long)(b * S_ + s);
  const float* qrow = qkv + trow * 2304 + hd * 64;
  if (tid < 64) qs[tid] = qrow[tid];
  bool dq = dep[b * S_ + s] >= depth;
  __syncthreads();

  // phase 1: scores = q.k/8 + (causal && dq && dk ? 1 : 0)
  float lmax = -1e30f;
  for (int k = tid; k < S_; k += 256){
    const float* krow = qkv + (long)(b * S_ + k) * 2304 + 768 + hd * 64;
    float dot = 0.f;
    #pragma unroll
    for (int d4 = 0; d4 < 64; d4 += 4){
      float4 kv = *(const float4*)(krow + d4);
      dot = fmaf(qs[d4+0], kv.x, dot);
      dot = fmaf(qs[d4+1], kv.y, dot);
      dot = fmaf(qs[d4+2], kv.z, dot);
      dot = fmaf(qs[d4+3], kv.w, dot);
    }
    float boost = (k <= s && dq && dep[b * S_ + k] >= depth) ? 1.0f : 0.0f;
    float sv = dot * 0.125f + boost;
    sc[k] = sv;
    lmax = fmaxf(lmax, sv);
  }
  float wm = waveMax(lmax);
  if ((tid & 63) == 0) rmax[tid >> 6] = wm;
  __syncthreads();
  float bmax = fmaxf(fmaxf(rmax[0], rmax[1]), fmaxf(rmax[2], rmax[3]));

  // phase 2: exp + sum
  float lsum = 0.f;
  for (int k = tid; k < S_; k += 256){
    float p = expf(sc[k] - bmax);
    sc[k] = p;
    lsum += p;
  }
  float wsv = waveSum(lsum);
  if ((tid & 63) == 0) rsum[tid >> 6] = wsv;
  __syncthreads();
  float inv = 1.0f / (rsum[0] + rsum[1] + rsum[2] + rsum[3]);

  // phase 3: P @ V  (wave w handles keys [w*256, w*256+256), lane = d)
  int d = tid & 63, ch = tid >> 6;
  float acc = 0.f;
  const float* vbase = qkv + (long)(b * S_) * 2304 + 1536 + hd * 64 + d;
  for (int k = ch * 256; k < ch * 256 + 256; ++k)
    acc = fmaf(sc[k], vbase[(long)k * 2304], acc);
  ov[ch][d] = acc;
  __syncthreads();
  if (tid < 64){
    float r = (ov[0][tid] + ov[1][tid] + ov[2][tid] + ov[3][tid]) * inv;
    out[trow * 768 + hd * 64 + tid] = r;
  }
}

// ---------------- router aux loss ----------------
__global__ __launch_bounds__(256) void loss_k(const float* __restrict__ rl,
                                              const int* __restrict__ dep,
                                              float* __restrict__ out){
  float p[4] = {0, 0, 0, 0};
  float ds = 0.f;
  for (int t = threadIdx.x; t < NT; t += 256){
    float l0 = rl[t*4+0], l1 = rl[t*4+1], l2 = rl[t*4+2], l3 = rl[t*4+3];
    float m = fmaxf(fmaxf(l0, l1), fmaxf(l2, l3));
    float e0 = expf(l0 - m), e1 = expf(l1 - m), e2 = expf(l2 - m), e3 = expf(l3 - m);
    float inv = 1.0f / (e0 + e1 + e2 + e3);
    p[0] += e0 * inv; p[1] += e1 * inv; p[2] += e2 * inv; p[3] += e3 * inv;
    ds += (float)dep[t];
  }
  __shared__ float red[4][5];
  float a0 = waveSum(p[0]), a1 = waveSum(p[1]), a2 = waveSum(p[2]), a3 = waveSum(p[3]);
  float a4 = waveSum(ds);
  int wid = threadIdx.x >> 6;
  if ((threadIdx.x & 63) == 0){
    red[wid][0] = a0; red[wid][1] = a1; red[wid][2] = a2; red[wid][3] = a3; red[wid][4] = a4;
  }
  __syncthreads();
  if (threadIdx.x == 0){
    float mp[4];
    for (int d = 0; d < 4; d++) mp[d] = red[0][d] + red[1][d] + red[2][d] + red[3][d];
    float dsum = red[0][4] + red[1][4] + red[2][4] + red[3][4];
    const float u = 0.25f;
    float lb = 0.f;
    for (int d = 0; d < 4; d++){
      float mean = mp[d] / (float)NT;
      lb += u * (logf(u) - logf(mean));
    }
    lb *= 0.25f;                                   // / MAXD
    float sparsity = dsum / (float)NT * 0.25f;     // mean(depths)/MAXD
    out[0] = 0.01f * lb + 0.001f * sparsity;
  }
}

extern "C" void kernel_launch(void* const* d_in, const int* in_sizes, int n_in,
                              void* d_out, int out_size, void* d_ws, size_t ws_size,
                              hipStream_t stream){
  const int*   ids  = (const int*)d_in[0];
  const float* tok  = (const float*)d_in[1];
  const float* pos  = (const float*)d_in[2];
  const float* rw1  = (const float*)d_in[3];
  const float* rb1  = (const float*)d_in[4];
  const float* rw2  = (const float*)d_in[5];
  const float* rb2  = (const float*)d_in[6];
  const float* wqkv = (const float*)d_in[7];
  const float* bqkv = (const float*)d_in[8];
  const float* wo   = (const float*)d_in[9];
  const float* bo   = (const float*)d_in[10];
  const float* ln1g = (const float*)d_in[11];
  const float* ln1b = (const float*)d_in[12];
  const float* ln2g = (const float*)d_in[13];
  const float* ln2b = (const float*)d_in[14];
  const float* w1   = (const float*)d_in[15];
  const float* b1   = (const float*)d_in[16];
  const float* w2   = (const float*)d_in[17];
  const float* b2   = (const float*)d_in[18];
  const float* lnfg = (const float*)d_in[19];
  const float* lnfb = (const float*)d_in[20];
  const float* lmh  = (const float*)d_in[21];

  // workspace layout (~44 MB)
  float* ws   = (float*)d_ws;
  float* h    = ws;                       // [2048,768]
  float* lnb  = h   + (long)NT * E_;      // [2048,768]
  float* big  = lnb + (long)NT * E_;      // [2048,3072] (qkv uses [2048,2304])
  float* attn = big + (long)NT * I_;      // [2048,768]
  int*   dep  = (int*)(attn + (long)NT * E_); // [2048]

  // output layout: logits | depths | loss | router_logits
  float* out        = (float*)d_out;
  float* out_logits = out;
  float* out_dep    = out + (long)NT * V_;
  float* out_loss   = out_dep + NT;
  float* out_rl     = out_loss + 1;

  embed_k<<<NT, 256, 0, stream>>>(ids, tok, pos, h);
  router_k<<<NT, 128, 0, stream>>>(h, rw1, rb1, rw2, rb2, dep, out_dep, out_rl);

  for (int depth = 1; depth <= MAXD_; ++depth){
    int li = depth - 1;   // (depth-1) % L with L==MAXD
    ln_k<<<NT, 256, 0, stream>>>(h, ln1g + li * E_, ln1b + li * E_, lnb);
    gemm_bt<EPI_NONE><<<dim3(36, 32), 256, 0, stream>>>(
        lnb, wqkv + (long)li * 3 * E_ * E_, bqkv + li * 3 * E_, nullptr, big, NT, 3 * E_, E_);
    attn_k<<<dim3(S_, H_, B_), 256, 0, stream>>>(big, dep, attn, depth);
    gemm_bt<EPI_RES><<<dim3(12, 32), 256, 0, stream>>>(
        attn, wo + (long)li * E_ * E_, bo + li * E_, h, h, NT, E_, E_);
    ln_k<<<NT, 256, 0, stream>>>(h, ln2g + li * E_, ln2b + li * E_, lnb);
    gemm_bt<EPI_GELU><<<dim3(48, 32), 256, 0, stream>>>(
        lnb, w1 + (long)li * I_ * E_, b1 + li * I_, nullptr, big, NT, I_, E_);
    gemm_bt<EPI_RES><<<dim3(12, 32), 256, 0, stream>>>(
        big, w2 + (long)li * E_ * I_, b2 + li * E_, h, h, NT, E_, I_);
  }

  ln_k<<<NT, 256, 0, stream>>>(h, lnfg, lnfb, lnb);
  gemm_bt<EPI_NONE><<<dim3((V_ + 63) / 64, 32), 256, 0, stream>>>(
      lnb, lmh, nullptr, nullptr, out_logits, NT, V_, E_);
  loss_k<<<1, 256, 0, stream>>>(out_rl, dep, out_loss);
}